// Round 1
// baseline (226.045 us; speedup 1.0000x reference)
//
#include <hip/hip_runtime.h>
#include <stdint.h>

#define N_ROWS 8192
#define DIM    128
#define NCODES 16384
#define TAU    0.01f
#define MARGIN 0.20f
#define CAP    256

typedef __attribute__((ext_vector_type(4))) float f32x4;
typedef __attribute__((ext_vector_type(8))) short s16x8;

// ---------------- workspace layout (bytes) ----------------
// [0       , 2 MiB)  : x_bf16   ushort[8192*128]
// [2 MiB   , 6 MiB)  : cb_bf16  ushort[16384*128]
// [6 MiB   , +32KiB) : cnt      int[8192]
// [8 MiB   , 16 MiB) : cand     int[8192*256]

__device__ inline unsigned short f2bf(float f) {
    union { float f; unsigned int u; } v; v.f = f;
    unsigned int r = v.u + 0x7FFFu + ((v.u >> 16) & 1u);  // RNE
    return (unsigned short)(r >> 16);
}

// ---------------- kernel A: convert + zero counters ----------------
__global__ void convert_kernel(const float* __restrict__ x, const float* __restrict__ cb,
                               unsigned short* __restrict__ xbf, unsigned short* __restrict__ cbbf,
                               int* __restrict__ cnt) {
    const int XN = N_ROWS * DIM;          // 1048576
    const int CN = NCODES * DIM;          // 2097152
    const int total = XN + CN + N_ROWS;
    for (int i = blockIdx.x * blockDim.x + threadIdx.x; i < total;
         i += gridDim.x * blockDim.x) {
        if (i < XN) {
            xbf[i] = f2bf(x[i]);
        } else if (i < XN + CN) {
            cbbf[i - XN] = f2bf(cb[i - XN]);
        } else {
            cnt[i - XN - CN] = 0;
        }
    }
}

// ---------------- kernel B: bf16 MFMA scores + thresholded candidate emission ----------------
// Block: 64 x-rows x 4096 cb cols (grid = 128 row-groups * 4 c-splits = 512 blocks).
// Wave w owns a 64-cb strip of each 256-cb chunk; 16 chunks per block.
// D-tile: m = cb index, n = x row. A frag = cb rows (contiguous 16B), B frag = x rows (contiguous 16B).
__global__ __launch_bounds__(256, 2) void gemm_topk_kernel(
        const unsigned short* __restrict__ xbf, const unsigned short* __restrict__ cbbf,
        int* __restrict__ cnt, int* __restrict__ cand) {
    const int bx     = blockIdx.x;
    const int rowgrp = bx >> 2;
    const int csplit = bx & 3;
    const int row0   = rowgrp * 64;
    const int cb0    = csplit * 4096;
    const int wave   = threadIdx.x >> 6;
    const int lane   = threadIdx.x & 63;
    const int r      = lane & 15;   // A: m index / B: n index
    const int q      = lane >> 4;   // quad

    __shared__ int rm[64];          // int-punned running row max
    if (threadIdx.x < 64) rm[threadIdx.x] = (int)0x80000000u;  // -0.0f
    __syncthreads();

    // preload B (x) fragments for 4 x-tiles x 4 k-steps; register-resident all block
    s16x8 bfrag[4][4];
#pragma unroll
    for (int xt = 0; xt < 4; ++xt)
#pragma unroll
        for (int kk = 0; kk < 4; ++kk)
            bfrag[xt][kk] = *reinterpret_cast<const s16x8*>(
                &xbf[(size_t)(row0 + xt * 16 + r) * DIM + kk * 32 + q * 8]);

    for (int it = 0; it < 16; ++it) {
        const int cbase = cb0 + it * 256 + wave * 64;
        f32x4 acc[4][4];  // [cb-tile][x-tile]
#pragma unroll
        for (int ct = 0; ct < 4; ++ct)
#pragma unroll
            for (int xt = 0; xt < 4; ++xt)
                acc[ct][xt] = (f32x4){0.f, 0.f, 0.f, 0.f};

#pragma unroll
        for (int kk = 0; kk < 4; ++kk) {
            s16x8 afrag[4];
#pragma unroll
            for (int ct = 0; ct < 4; ++ct)
                afrag[ct] = *reinterpret_cast<const s16x8*>(
                    &cbbf[(size_t)(cbase + ct * 16 + r) * DIM + kk * 32 + q * 8]);
#pragma unroll
            for (int ct = 0; ct < 4; ++ct)
#pragma unroll
                for (int xt = 0; xt < 4; ++xt)
                    acc[ct][xt] = __builtin_amdgcn_mfma_f32_16x16x32_bf16(
                        afrag[ct], bfrag[xt][kk], acc[ct][xt], 0, 0, 0);
        }

        // per-lane max over its 16 scores of row (row0 + xt*16 + r); update running row max
        float mxs[4];
#pragma unroll
        for (int xt = 0; xt < 4; ++xt) {
            float mx = acc[0][xt][0];
#pragma unroll
            for (int ct = 0; ct < 4; ++ct)
#pragma unroll
                for (int j = 0; j < 4; ++j)
                    mx = fmaxf(mx, acc[ct][xt][j]);
            mxs[xt] = mx;
            const int rloc = xt * 16 + r;
            if (mx > __int_as_float(rm[rloc])) atomicMax(&rm[rloc], __float_as_int(mx));
        }
        if (it == 0) __syncthreads();  // warm thresholds before first emission

        // emission (rare slow path)
#pragma unroll
        for (int xt = 0; xt < 4; ++xt) {
            const int rloc = xt * 16 + r;
            const float thr = __int_as_float(rm[rloc]) - MARGIN;
            if (mxs[xt] > thr) {
                const int grow = row0 + rloc;
#pragma unroll
                for (int ct = 0; ct < 4; ++ct)
#pragma unroll
                    for (int j = 0; j < 4; ++j)
                        if (acc[ct][xt][j] > thr) {
                            int pos = atomicAdd(&cnt[grow], 1);
                            if (pos < CAP)
                                cand[(size_t)grow * CAP + pos] = cbase + ct * 16 + q * 4 + j;
                        }
            }
        }
    }
}

// ---------------- kernel C: exact fp32 rescore + top-3 + softmax + combine ----------------
__device__ inline void topk3_insert(float s, int i, float& s1, int& i1,
                                    float& s2, int& i2, float& s3, int& i3) {
    if (s > s1 || (s == s1 && i < i1)) {
        s3 = s2; i3 = i2; s2 = s1; i2 = i1; s1 = s; i1 = i;
    } else if (s > s2 || (s == s2 && i < i2)) {
        s3 = s2; i3 = i2; s2 = s; i2 = i;
    } else if (s > s3 || (s == s3 && i < i3)) {
        s3 = s; i3 = i;
    }
}

__global__ __launch_bounds__(256) void finalize_kernel(
        const float* __restrict__ x, const float* __restrict__ cb,
        const int* __restrict__ cnt, const int* __restrict__ cand,
        float* __restrict__ out) {
    const int lane = threadIdx.x & 63;
    const int row  = blockIdx.x * 4 + (threadIdx.x >> 6);
    const int sub  = lane & 7;   // 8 lanes per candidate, 16 dims each
    const int grp  = lane >> 3;  // 8 candidates in flight

    int c = cnt[row];
    if (c > CAP) c = CAP;
    if (c < 0) c = 0;

    // lane's x slice: dims [sub*16, sub*16+16)
    float4 xq[4];
#pragma unroll
    for (int k = 0; k < 4; ++k)
        xq[k] = ((const float4*)x)[(size_t)row * 32 + sub * 4 + k];

    const int BIGI = 0x3FFFFFFF;
    float s1 = -1e30f, s2 = -1e30f, s3 = -1e30f;
    int   i1 = BIGI,   i2 = BIGI,   i3 = BIGI;

    const int rounds = (c + 7) >> 3;
    for (int t = 0; t < rounds; ++t) {
        const int ci  = t * 8 + grp;
        const int idx = (ci < c) ? cand[(size_t)row * CAP + ci] : -1;
        float p = 0.f;
        if (idx >= 0) {
            const float4* cbp = (const float4*)cb + (size_t)idx * 32 + sub * 4;
#pragma unroll
            for (int k = 0; k < 4; ++k) {
                float4 cv = cbp[k];
                p += xq[k].x * cv.x + xq[k].y * cv.y + xq[k].z * cv.z + xq[k].w * cv.w;
            }
        }
        p += __shfl_xor(p, 1);
        p += __shfl_xor(p, 2);
        p += __shfl_xor(p, 4);   // all 8 lanes of grp now hold the full fp32 dot
        if (idx >= 0) topk3_insert(p, idx, s1, i1, s2, i2, s3, i3);
    }

    // merge the 8 groups' top-3 (replicated within each group) into a final top-3
    float fs1 = -1e30f, fs2 = -1e30f, fs3 = -1e30f;
    int   fi1 = BIGI,   fi2 = BIGI,   fi3 = BIGI;
#pragma unroll
    for (int g = 0; g < 8; ++g) {
        float a1 = __shfl(s1, g * 8); int b1 = __shfl(i1, g * 8);
        float a2 = __shfl(s2, g * 8); int b2 = __shfl(i2, g * 8);
        float a3 = __shfl(s3, g * 8); int b3 = __shfl(i3, g * 8);
        topk3_insert(a1, b1, fs1, fi1, fs2, fi2, fs3, fi3);
        topk3_insert(a2, b2, fs1, fi1, fs2, fi2, fs3, fi3);
        topk3_insert(a3, b3, fs1, fi1, fs2, fi2, fs3, fi3);
    }

    // exact softmax over {top-3 scores} U {C-3 zeros}, scaled by 1/TAU
    const float m  = fmaxf(fs1, 0.f);
    const float e1 = (fi1 != BIGI) ? __expf((fs1 - m) / TAU) : 0.f;
    const float e2 = (fi2 != BIGI) ? __expf((fs2 - m) / TAU) : 0.f;
    const float e3 = (fi3 != BIGI) ? __expf((fs3 - m) / TAU) : 0.f;
    const float denom = e1 + e2 + e3 + (float)(NCODES - 3) * __expf(-m / TAU);
    const float w1 = e1 / denom, w2 = e2 / denom, w3 = e3 / denom;

    // z_q: each lane handles 2 dims
    const float2* cb2 = (const float2*)cb;
    float ox = 0.f, oy = 0.f;
    if (fi1 != BIGI) { float2 v = cb2[(size_t)fi1 * 64 + lane]; ox += w1 * v.x; oy += w1 * v.y; }
    if (fi2 != BIGI) { float2 v = cb2[(size_t)fi2 * 64 + lane]; ox += w2 * v.x; oy += w2 * v.y; }
    if (fi3 != BIGI) { float2 v = cb2[(size_t)fi3 * 64 + lane]; ox += w3 * v.x; oy += w3 * v.y; }
    ((float2*)out)[(size_t)row * 64 + lane] = make_float2(ox, oy);
}

// ---------------- launch ----------------
extern "C" void kernel_launch(void* const* d_in, const int* in_sizes, int n_in,
                              void* d_out, int out_size, void* d_ws, size_t ws_size,
                              hipStream_t stream) {
    const float* x  = (const float*)d_in[0];
    const float* cb = (const float*)d_in[1];
    char* ws = (char*)d_ws;

    unsigned short* xbf  = (unsigned short*)ws;                       // 2 MiB
    unsigned short* cbbf = (unsigned short*)(ws + (2u << 20));        // 4 MiB
    int* cnt  = (int*)(ws + (6u << 20));                              // 32 KiB
    int* cand = (int*)(ws + (8u << 20));                              // 8 MiB
    float* out = (float*)d_out;

    hipLaunchKernelGGL(convert_kernel,   dim3(2048), dim3(256), 0, stream, x, cb, xbf, cbbf, cnt);
    hipLaunchKernelGGL(gemm_topk_kernel, dim3(512),  dim3(256), 0, stream, xbf, cbbf, cnt, cand);
    hipLaunchKernelGGL(finalize_kernel,  dim3(2048), dim3(256), 0, stream, x, cb, cnt, cand, out);
}